// Round 1
// baseline (289.115 us; speedup 1.0000x reference)
//
#include <hip/hip_runtime.h>
#include <math.h>

// Problem constants
constexpr int Dn = 4096;     // C*H*W
constexpr int Bn = 4096;     // batch
constexpr int NCLS = 10;

// Workspace layout (in float units)
// S      : [0, 40960)            10 x 4096 class sums (fp32, atomic)
// n_c    : [40960, 40970)        int counts
// ce_sum : [40970]               fp32 atomic
// a      : [41000, 45096)        per-sample scale 1/||g-gmin||
// b      : [45096, 49192)        per-sample -gmin*a
// cls    : [49192, 53288)        int predicted class
constexpr int OFF_S   = 0;
constexpr int OFF_N   = 40960;
constexpr int OFF_CE  = 40970;
constexpr int ZERO_FLOATS = 40971;  // memset region covers S, n_c, ce_sum
constexpr int OFF_A   = 41000;
constexpr int OFF_B   = 45096;
constexpr int OFF_CLS = 49192;

__global__ __launch_bounds__(256) void pass1_stats(
    const float* __restrict__ grad, const float* __restrict__ outputs,
    const int* __restrict__ y, float* __restrict__ ws)
{
    const int i = blockIdx.x;
    const int t = threadIdx.x;
    const int wave = t >> 6, lane = t & 63;

    const float4* g4 = (const float4*)(grad + (size_t)i * Dn);
    float4 v[4];
    #pragma unroll
    for (int k = 0; k < 4; ++k) v[k] = g4[t + 256 * k];

    // --- block min reduce ---
    float mn = v[0].x;
    #pragma unroll
    for (int k = 0; k < 4; ++k)
        mn = fminf(mn, fminf(fminf(v[k].x, v[k].y), fminf(v[k].z, v[k].w)));
    #pragma unroll
    for (int off = 32; off; off >>= 1) mn = fminf(mn, __shfl_down(mn, off, 64));
    __shared__ float sred[4];
    __shared__ float sred2[4];
    if (lane == 0) sred[wave] = mn;
    __syncthreads();
    if (t == 0)
        sred[0] = fminf(fminf(sred[0], sred[1]), fminf(sred[2], sred[3]));
    __syncthreads();
    const float gmin = sred[0];

    // --- block sum of squares of (g - gmin) ---
    float ss = 0.f;
    #pragma unroll
    for (int k = 0; k < 4; ++k) {
        float dx = v[k].x - gmin, dy = v[k].y - gmin;
        float dz = v[k].z - gmin, dw = v[k].w - gmin;
        ss += dx * dx + dy * dy + dz * dz + dw * dw;
    }
    #pragma unroll
    for (int off = 32; off; off >>= 1) ss += __shfl_down(ss, off, 64);
    if (lane == 0) sred2[wave] = ss;
    __syncthreads();

    if (t == 0) {
        float sum = sred2[0] + sred2[1] + sred2[2] + sred2[3];
        float s = 1.0f / sqrtf(sum);               // range cancels: vn = (g-gmin)*s
        ws[OFF_A + i] = s;
        ws[OFF_B + i] = -gmin * s;

        // logits: argmax (first-max, strict >) + log-softmax CE
        const float* o = outputs + (size_t)i * NCLS;
        float m = o[0]; int am = 0;
        #pragma unroll
        for (int k = 1; k < NCLS; ++k) { float ok = o[k]; if (ok > m) { m = ok; am = k; } }
        float se = 0.f;
        #pragma unroll
        for (int k = 0; k < NCLS; ++k) se += expf(o[k] - m);
        float lse = m + logf(se);
        float ce = lse - o[y[i]];
        atomicAdd(&ws[OFF_CE], ce);
        ((int*)ws)[OFF_CLS + i] = am;
        atomicAdd(&((int*)ws)[OFF_N + am], 1);
    }
}

// grid: (4 j-tiles, 64 i-chunks), block 256. Thread t covers float4 index
// j4 = jt*256+t (dims 4*j4..4*j4+3), loops 64 samples of its chunk.
__global__ __launch_bounds__(256) void pass2_classsum(
    const float* __restrict__ grad, float* __restrict__ ws)
{
    const int jt = blockIdx.x;
    const int i0 = blockIdx.y * 64;
    const int t = threadIdx.x;
    const int j4 = jt * 256 + t;   // 0..1023 (float4 units across D)

    __shared__ float la[64], lb[64];
    __shared__ int lc[64];
    if (t < 64) {
        la[t] = ws[OFF_A + i0 + t];
        lb[t] = ws[OFF_B + i0 + t];
        lc[t] = ((const int*)ws)[OFF_CLS + i0 + t];
    }
    __syncthreads();

    float4 acc[NCLS];
    #pragma unroll
    for (int c = 0; c < NCLS; ++c) acc[c] = make_float4(0.f, 0.f, 0.f, 0.f);

    const float4* g4 = (const float4*)grad;
    #pragma unroll 4
    for (int i = 0; i < 64; ++i) {
        float4 gv = g4[(size_t)(i0 + i) * (Dn / 4) + j4];
        const float ai = la[i], bi = lb[i];
        const int ci = lc[i];               // wave-uniform
        float vx = fmaf(gv.x, ai, bi);
        float vy = fmaf(gv.y, ai, bi);
        float vz = fmaf(gv.z, ai, bi);
        float vw = fmaf(gv.w, ai, bi);
        #pragma unroll
        for (int c = 0; c < NCLS; ++c) {
            float m = (ci == c) ? 1.0f : 0.0f;
            acc[c].x = fmaf(vx, m, acc[c].x);
            acc[c].y = fmaf(vy, m, acc[c].y);
            acc[c].z = fmaf(vz, m, acc[c].z);
            acc[c].w = fmaf(vw, m, acc[c].w);
        }
    }

    float* S = ws + OFF_S;
    #pragma unroll
    for (int c = 0; c < NCLS; ++c) {
        int base = c * Dn + j4 * 4;
        atomicAdd(&S[base + 0], acc[c].x);
        atomicAdd(&S[base + 1], acc[c].y);
        atomicAdd(&S[base + 2], acc[c].z);
        atomicAdd(&S[base + 3], acc[c].w);
    }
}

__global__ __launch_bounds__(256) void pass3_final(
    const float* __restrict__ ws, float* __restrict__ out)
{
    const int t = threadIdx.x;
    const int wave = t >> 6, lane = t & 63;
    double local = 0.0;
    for (int idx = t; idx < NCLS * Dn; idx += 256) {
        double s = (double)ws[OFF_S + idx];
        local += s * s;
    }
    #pragma unroll
    for (int off = 32; off; off >>= 1) local += __shfl_down(local, off, 64);
    __shared__ double sr[4];
    if (lane == 0) sr[wave] = local;
    __syncthreads();
    if (t == 0) {
        double ssum = sr[0] + sr[1] + sr[2] + sr[3];
        const int* n = (const int*)ws + OFF_N;
        double n2 = 0.0;
        for (int c = 0; c < NCLS; ++c) { double nc = (double)n[c]; n2 += nc * nc; }
        double xloss = (n2 - ssum) / (2.0 * (double)Bn);
        double celoss = (double)ws[OFF_CE] / (double)Bn;
        out[0] = (float)(celoss + xloss);
    }
}

extern "C" void kernel_launch(void* const* d_in, const int* in_sizes, int n_in,
                              void* d_out, int out_size, void* d_ws, size_t ws_size,
                              hipStream_t stream)
{
    const float* outputs = (const float*)d_in[0];   // [4096,10] f32
    const float* grad    = (const float*)d_in[1];   // [4096,1,64,64] f32
    const int*   y       = (const int*)d_in[2];     // [4096] i32
    float* ws  = (float*)d_ws;
    float* out = (float*)d_out;

    hipMemsetAsync(d_ws, 0, ZERO_FLOATS * sizeof(float), stream);
    pass1_stats<<<Bn, 256, 0, stream>>>(grad, outputs, y, ws);
    pass2_classsum<<<dim3(4, 64), 256, 0, stream>>>(grad, ws);
    pass3_final<<<1, 256, 0, stream>>>(ws, out);
}

// Round 2
// 158.830 us; speedup vs baseline: 1.8203x; 1.8203x over previous
//
#include <hip/hip_runtime.h>
#include <math.h>

// Problem constants
constexpr int Dn = 4096;     // C*H*W
constexpr int Bn = 4096;     // batch
constexpr int NCLS = 10;

// Workspace layout (float units)
constexpr int OFF_N    = 0;      // 10 ints: class counts
constexpr int OFF_CE   = 10;     // 1 float: CE sum
constexpr int OFF_XS   = 11;     // 1 float: sum of S^2
constexpr int OFF_A    = 16;     // 4096 floats: per-sample scale
constexpr int OFF_B2   = 4112;   // 4096 floats: per-sample offset
constexpr int OFF_CLS  = 8208;   // 4096 ints: predicted class
constexpr int OFF_S    = 12304;  // ncopies x (10*4096) class-sum copies
constexpr int SCOPY    = NCLS * Dn;   // 40960 floats per copy
constexpr int MAXCOPY  = 8;

// ---------------------------------------------------------------- pass 0
// CE + argmax + class histogram. 16 blocks x 256, one sample/thread.
// Atomics: 1 CE add + 10 count adds per BLOCK (vs per-sample before).
__global__ __launch_bounds__(256) void pass0_ce(
    const float* __restrict__ outputs, const int* __restrict__ y,
    float* __restrict__ ws)
{
    const int t = threadIdx.x;
    const int i = blockIdx.x * 256 + t;
    const int wave = t >> 6, lane = t & 63;

    const float* o = outputs + (size_t)i * NCLS;
    float m = o[0]; int am = 0;
    #pragma unroll
    for (int k = 1; k < NCLS; ++k) { float ok = o[k]; if (ok > m) { m = ok; am = k; } }
    float se = 0.f;
    #pragma unroll
    for (int k = 0; k < NCLS; ++k) se += expf(o[k] - m);
    float ce = m + logf(se) - o[y[i]];
    ((int*)ws)[OFF_CLS + i] = am;

    // block-reduce ce
    #pragma unroll
    for (int off = 32; off; off >>= 1) ce += __shfl_down(ce, off, 64);
    __shared__ float sce[4];
    __shared__ int hist[NCLS];
    if (t < NCLS) hist[t] = 0;
    if (lane == 0) sce[wave] = ce;
    __syncthreads();
    atomicAdd(&hist[am], 1);   // LDS atomic
    __syncthreads();
    if (t == 0) atomicAdd(&ws[OFF_CE], sce[0] + sce[1] + sce[2] + sce[3]);
    if (t < NCLS) atomicAdd(&((int*)ws)[OFF_N + t], hist[t]);
}

// ---------------------------------------------------------------- pass 1
// Per-sample min + sum-of-squares -> affine coeffs. NO atomics.
__global__ __launch_bounds__(256) void pass1_stats(
    const float* __restrict__ grad, float* __restrict__ ws)
{
    const int i = blockIdx.x;
    const int t = threadIdx.x;
    const int wave = t >> 6, lane = t & 63;

    const float4* g4 = (const float4*)(grad + (size_t)i * Dn);
    float4 v[4];
    #pragma unroll
    for (int k = 0; k < 4; ++k) v[k] = g4[t + 256 * k];

    float mn = v[0].x;
    #pragma unroll
    for (int k = 0; k < 4; ++k)
        mn = fminf(mn, fminf(fminf(v[k].x, v[k].y), fminf(v[k].z, v[k].w)));
    #pragma unroll
    for (int off = 32; off; off >>= 1) mn = fminf(mn, __shfl_down(mn, off, 64));
    __shared__ float sred[4];
    __shared__ float sred2[4];
    if (lane == 0) sred[wave] = mn;
    __syncthreads();
    if (t == 0)
        sred[0] = fminf(fminf(sred[0], sred[1]), fminf(sred[2], sred[3]));
    __syncthreads();
    const float gmin = sred[0];

    float ss = 0.f;
    #pragma unroll
    for (int k = 0; k < 4; ++k) {
        float dx = v[k].x - gmin, dy = v[k].y - gmin;
        float dz = v[k].z - gmin, dw = v[k].w - gmin;
        ss += dx * dx + dy * dy + dz * dz + dw * dw;
    }
    #pragma unroll
    for (int off = 32; off; off >>= 1) ss += __shfl_down(ss, off, 64);
    if (lane == 0) sred2[wave] = ss;
    __syncthreads();

    if (t == 0) {
        float sum = sred2[0] + sred2[1] + sred2[2] + sred2[3];
        float s = 1.0f / sqrtf(sum);           // min-max range cancels under L2-norm
        ws[OFF_A + i] = s;
        ws[OFF_B2 + i] = -gmin * s;
    }
}

// ---------------------------------------------------------------- pass 2
// Class-sum accumulation. grid (4 j-tiles, 64 i-chunks), block 256.
// Atomics spread over ncopies replicated S buffers.
__global__ __launch_bounds__(256) void pass2_classsum(
    const float* __restrict__ grad, float* __restrict__ ws, int ncopies)
{
    const int jt = blockIdx.x;
    const int i0 = blockIdx.y * 64;
    const int t = threadIdx.x;
    const int j4 = jt * 256 + t;   // float4 index across D

    __shared__ float la[64], lb[64];
    __shared__ int lc[64];
    if (t < 64) {
        la[t] = ws[OFF_A + i0 + t];
        lb[t] = ws[OFF_B2 + i0 + t];
        lc[t] = ((const int*)ws)[OFF_CLS + i0 + t];
    }
    __syncthreads();

    float4 acc[NCLS];
    #pragma unroll
    for (int c = 0; c < NCLS; ++c) acc[c] = make_float4(0.f, 0.f, 0.f, 0.f);

    const float4* g4 = (const float4*)grad;
    #pragma unroll 4
    for (int i = 0; i < 64; ++i) {
        float4 gv = g4[(size_t)(i0 + i) * (Dn / 4) + j4];
        const float ai = la[i], bi = lb[i];
        const int ci = lc[i];               // wave-uniform
        float vx = fmaf(gv.x, ai, bi);
        float vy = fmaf(gv.y, ai, bi);
        float vz = fmaf(gv.z, ai, bi);
        float vw = fmaf(gv.w, ai, bi);
        #pragma unroll
        for (int c = 0; c < NCLS; ++c) {
            float m = (ci == c) ? 1.0f : 0.0f;
            acc[c].x = fmaf(vx, m, acc[c].x);
            acc[c].y = fmaf(vy, m, acc[c].y);
            acc[c].z = fmaf(vz, m, acc[c].z);
            acc[c].w = fmaf(vw, m, acc[c].w);
        }
    }

    float* S = ws + OFF_S + (size_t)(blockIdx.y % ncopies) * SCOPY;
    #pragma unroll
    for (int c = 0; c < NCLS; ++c) {
        int base = c * Dn + j4 * 4;
        atomicAdd(&S[base + 0], acc[c].x);
        atomicAdd(&S[base + 1], acc[c].y);
        atomicAdd(&S[base + 2], acc[c].z);
        atomicAdd(&S[base + 3], acc[c].w);
    }
}

// ---------------------------------------------------------------- pass 3
// Sum of squares of (sum over copies). 160 blocks x 256 covers 40960.
__global__ __launch_bounds__(256) void pass3_sq(
    const float* __restrict__ ws_c, float* __restrict__ ws, int ncopies)
{
    const int t = threadIdx.x;
    const int idx = blockIdx.x * 256 + t;
    const int wave = t >> 6, lane = t & 63;

    float s = 0.f;
    for (int k = 0; k < ncopies; ++k)
        s += ws_c[OFF_S + (size_t)k * SCOPY + idx];
    float p = s * s;
    #pragma unroll
    for (int off = 32; off; off >>= 1) p += __shfl_down(p, off, 64);
    __shared__ float sr[4];
    if (lane == 0) sr[wave] = p;
    __syncthreads();
    if (t == 0) atomicAdd(&ws[OFF_XS], sr[0] + sr[1] + sr[2] + sr[3]);
}

// ---------------------------------------------------------------- pass 4
__global__ void pass4_final(const float* __restrict__ ws, float* __restrict__ out)
{
    const int* n = (const int*)ws + OFF_N;
    double n2 = 0.0;
    #pragma unroll
    for (int c = 0; c < NCLS; ++c) { double nc = (double)n[c]; n2 += nc * nc; }
    double xloss = (n2 - (double)ws[OFF_XS]) / (2.0 * (double)Bn);
    double celoss = (double)ws[OFF_CE] / (double)Bn;
    out[0] = (float)(celoss + xloss);
}

extern "C" void kernel_launch(void* const* d_in, const int* in_sizes, int n_in,
                              void* d_out, int out_size, void* d_ws, size_t ws_size,
                              hipStream_t stream)
{
    const float* outputs = (const float*)d_in[0];   // [4096,10] f32
    const float* grad    = (const float*)d_in[1];   // [4096,1,64,64] f32
    const int*   y       = (const int*)d_in[2];     // [4096] i32
    float* ws  = (float*)d_ws;
    float* out = (float*)d_out;

    // how many replicated S buffers fit in ws?
    size_t avail = ws_size / sizeof(float);
    int ncopies = 1;
    if (avail > (size_t)OFF_S + SCOPY) {
        ncopies = (int)((avail - OFF_S) / SCOPY);
        if (ncopies > MAXCOPY) ncopies = MAXCOPY;
        if (ncopies < 1) ncopies = 1;
    }

    size_t zero_bytes = ((size_t)OFF_S + (size_t)ncopies * SCOPY) * sizeof(float);
    hipMemsetAsync(d_ws, 0, zero_bytes, stream);
    pass0_ce<<<Bn / 256, 256, 0, stream>>>(outputs, y, ws);
    pass1_stats<<<Bn, 256, 0, stream>>>(grad, ws);
    pass2_classsum<<<dim3(4, 64), 256, 0, stream>>>(grad, ws, ncopies);
    pass3_sq<<<SCOPY / 256, 256, 0, stream>>>(ws, ws, ncopies);
    pass4_final<<<1, 1, 0, stream>>>(ws, out);
}

// Round 3
// 129.628 us; speedup vs baseline: 2.2304x; 1.2253x over previous
//
#include <hip/hip_runtime.h>
#include <math.h>

constexpr int Dn = 4096;     // C*H*W
constexpr int Bn = 4096;     // batch
constexpr int NCLS = 10;

// Workspace layout (float/int units)
constexpr int OFF_CUR   = 0;      // 10 ints: class cursors -> final class counts
constexpr int OFF_CE    = 10;     // 1 float: CE sum
constexpr int OFF_XS    = 11;     // 1 float: sum of S^2
constexpr int OFF_NCH   = 12;     // 1 int: number of chunks
constexpr int OFF_CHS   = 16;     // 11 ints: per-class chunk range starts
constexpr int OFF_A     = 32;     // 4096 floats: per-sample scale
constexpr int OFF_B2    = 4128;   // 4096 floats: per-sample offset
constexpr int OFF_ORD   = 8224;   // 10*4096 ints: per-class sample index lists
constexpr int OFF_CHMAP = 49184;  // up to 272 ints: chunk -> (class<<16)|start
constexpr int OFF_P     = 49456;  // partials: maxchunks * 4096 floats (16B aligned)

// ---------------------------------------------------------------- pass 0
// CE + argmax + per-class ordering. 16 blocks x 256, one sample/thread.
__global__ __launch_bounds__(256) void pass0_ce_order(
    const float* __restrict__ outputs, const int* __restrict__ y,
    float* __restrict__ ws)
{
    const int t = threadIdx.x;
    const int i = blockIdx.x * 256 + t;
    const int wave = t >> 6, lane = t & 63;
    int* wsi = (int*)ws;

    __shared__ int hist[NCLS];
    __shared__ int lbase[NCLS];
    __shared__ float sce[4];
    if (t < NCLS) hist[t] = 0;
    __syncthreads();

    const float* o = outputs + (size_t)i * NCLS;
    float m = o[0]; int am = 0;
    #pragma unroll
    for (int k = 1; k < NCLS; ++k) { float ok = o[k]; if (ok > m) { m = ok; am = k; } }
    float se = 0.f;
    #pragma unroll
    for (int k = 0; k < NCLS; ++k) se += expf(o[k] - m);
    float ce = m + logf(se) - o[y[i]];

    int rank = atomicAdd(&hist[am], 1);   // LDS atomic: rank within block+class

    #pragma unroll
    for (int off = 32; off; off >>= 1) ce += __shfl_down(ce, off, 64);
    if (lane == 0) sce[wave] = ce;
    __syncthreads();

    if (t < NCLS) lbase[t] = atomicAdd(&wsi[OFF_CUR + t], hist[t]);
    if (t == 0) atomicAdd(&ws[OFF_CE], sce[0] + sce[1] + sce[2] + sce[3]);
    __syncthreads();

    wsi[OFF_ORD + am * Bn + lbase[am] + rank] = i;
}

// ---------------------------------------------------------------- sched
// Build chunk map (class-major). Single thread; <= ~270 iterations.
__global__ void sched_chunks(float* __restrict__ ws, int CH)
{
    int* wsi = (int*)ws;
    int nch = 0;
    for (int c = 0; c < NCLS; ++c) {
        wsi[OFF_CHS + c] = nch;
        int n = wsi[OFF_CUR + c];
        for (int s = 0; s < n; s += CH)
            wsi[OFF_CHMAP + nch++] = (c << 16) | s;
    }
    wsi[OFF_CHS + NCLS] = nch;
    wsi[OFF_NCH] = nch;
}

// ---------------------------------------------------------------- pass 1
// Per-sample min + sum-of-squares -> affine coeffs (a, b). No atomics.
__global__ __launch_bounds__(256) void pass1_stats(
    const float* __restrict__ grad, float* __restrict__ ws)
{
    const int i = blockIdx.x;
    const int t = threadIdx.x;
    const int wave = t >> 6, lane = t & 63;

    const float4* g4 = (const float4*)(grad + (size_t)i * Dn);
    float4 v[4];
    #pragma unroll
    for (int k = 0; k < 4; ++k) v[k] = g4[t + 256 * k];

    float mn = v[0].x;
    #pragma unroll
    for (int k = 0; k < 4; ++k)
        mn = fminf(mn, fminf(fminf(v[k].x, v[k].y), fminf(v[k].z, v[k].w)));
    #pragma unroll
    for (int off = 32; off; off >>= 1) mn = fminf(mn, __shfl_down(mn, off, 64));
    __shared__ float sred[4];
    __shared__ float sred2[4];
    if (lane == 0) sred[wave] = mn;
    __syncthreads();
    if (t == 0)
        sred[0] = fminf(fminf(sred[0], sred[1]), fminf(sred[2], sred[3]));
    __syncthreads();
    const float gmin = sred[0];

    float ss = 0.f;
    #pragma unroll
    for (int k = 0; k < 4; ++k) {
        float dx = v[k].x - gmin, dy = v[k].y - gmin;
        float dz = v[k].z - gmin, dw = v[k].w - gmin;
        ss += dx * dx + dy * dy + dz * dz + dw * dw;
    }
    #pragma unroll
    for (int off = 32; off; off >>= 1) ss += __shfl_down(ss, off, 64);
    if (lane == 0) sred2[wave] = ss;
    __syncthreads();

    if (t == 0) {
        float sum = sred2[0] + sred2[1] + sred2[2] + sred2[3];
        float s = 1.0f / sqrtf(sum);      // min-max range cancels under L2-norm
        ws[OFF_A + i] = s;
        ws[OFF_B2 + i] = -gmin * s;
    }
}

// ---------------------------------------------------------------- pass 2
// Class-sorted weighted row sums. grid (4 j-tiles, maxchunks).
// Plain (non-atomic) partial stores: 4 KB per block.
__global__ __launch_bounds__(256) void pass2_chunksum(
    const float* __restrict__ grad, float* __restrict__ ws, int CH)
{
    const int* wsi = (const int*)ws;
    const int chunk = blockIdx.y;
    if (chunk >= wsi[OFF_NCH]) return;
    const int t = threadIdx.x;

    const int e  = wsi[OFF_CHMAP + chunk];
    const int c  = e >> 16;
    const int s0 = e & 0xFFFF;
    const int m  = min(CH, wsi[OFF_CUR + c] - s0);

    __shared__ int   lidx[512];
    __shared__ float la[512], lb[512];
    for (int k = t; k < m; k += 256) {
        int idx = wsi[OFF_ORD + c * Bn + s0 + k];
        lidx[k] = idx;
        la[k] = ws[OFF_A + idx];
        lb[k] = ws[OFF_B2 + idx];
    }
    __syncthreads();

    const int j4 = blockIdx.x * 256 + t;   // float4 column index
    const float4* g4 = (const float4*)grad;

    float4 acc = make_float4(0.f, 0.f, 0.f, 0.f);
    float sb = 0.f;
    #pragma unroll 4
    for (int i = 0; i < m; ++i) {
        float4 gv = g4[(size_t)lidx[i] * (Dn / 4) + j4];
        float ai = la[i];
        acc.x = fmaf(gv.x, ai, acc.x);
        acc.y = fmaf(gv.y, ai, acc.y);
        acc.z = fmaf(gv.z, ai, acc.z);
        acc.w = fmaf(gv.w, ai, acc.w);
        sb += lb[i];
    }
    acc.x += sb; acc.y += sb; acc.z += sb; acc.w += sb;

    ((float4*)(ws + OFF_P))[(size_t)chunk * (Dn / 4) + j4] = acc;
}

// ---------------------------------------------------------------- pass 3
// Reduce partials over each class's chunk range, square, sum. 160 blocks.
__global__ __launch_bounds__(256) void pass3_sq(float* __restrict__ ws)
{
    const int t = threadIdx.x;
    const int idx = blockIdx.x * 256 + t;   // 0 .. 40959
    const int c = idx >> 12;                // class (uniform per block)
    const int j = idx & (Dn - 1);
    const int wave = t >> 6, lane = t & 63;
    const int* wsi = (const int*)ws;

    const int cs = wsi[OFF_CHS + c];
    const int ce2 = wsi[OFF_CHS + c + 1];
    const float* P = ws + OFF_P;

    float s = 0.f;
    for (int ch = cs; ch < ce2; ++ch)
        s += P[(size_t)ch * Dn + j];
    float p = s * s;

    #pragma unroll
    for (int off = 32; off; off >>= 1) p += __shfl_down(p, off, 64);
    __shared__ float sr[4];
    if (lane == 0) sr[wave] = p;
    __syncthreads();
    if (t == 0) atomicAdd(&ws[OFF_XS], sr[0] + sr[1] + sr[2] + sr[3]);
}

// ---------------------------------------------------------------- pass 4
__global__ void pass4_final(const float* __restrict__ ws, float* __restrict__ out)
{
    const int* n = (const int*)ws + OFF_CUR;
    double n2 = 0.0;
    #pragma unroll
    for (int c = 0; c < NCLS; ++c) { double nc = (double)n[c]; n2 += nc * nc; }
    double xloss = (n2 - (double)ws[OFF_XS]) / (2.0 * (double)Bn);
    double celoss = (double)ws[OFF_CE] / (double)Bn;
    out[0] = (float)(celoss + xloss);
}

extern "C" void kernel_launch(void* const* d_in, const int* in_sizes, int n_in,
                              void* d_out, int out_size, void* d_ws, size_t ws_size,
                              hipStream_t stream)
{
    const float* outputs = (const float*)d_in[0];   // [4096,10] f32
    const float* grad    = (const float*)d_in[1];   // [4096,1,64,64] f32
    const int*   y       = (const int*)d_in[2];     // [4096] i32
    float* ws  = (float*)d_ws;
    float* out = (float*)d_out;

    // pick chunk size CH so partial buffers fit in ws
    const size_t availf = ws_size / sizeof(float);
    const int cands[6] = {16, 32, 64, 128, 256, 512};
    int CH = 512, maxch = Bn / 512 + NCLS;
    for (int k = 0; k < 6; ++k) {
        int mc = Bn / cands[k] + NCLS;
        size_t need = (size_t)OFF_P + (size_t)mc * Dn;
        if (need <= availf) { CH = cands[k]; maxch = mc; break; }
    }

    hipMemsetAsync(d_ws, 0, 128, stream);   // cursors, CE, XS, NCH
    pass0_ce_order<<<Bn / 256, 256, 0, stream>>>(outputs, y, ws);
    sched_chunks<<<1, 1, 0, stream>>>(ws, CH);
    pass1_stats<<<Bn, 256, 0, stream>>>(grad, ws);
    pass2_chunksum<<<dim3(4, maxch), 256, 0, stream>>>(grad, ws, CH);
    pass3_sq<<<NCLS * Dn / 256, 256, 0, stream>>>(ws);
    pass4_final<<<1, 1, 0, stream>>>(ws, out);
}